// Round 1
// baseline (1316.545 us; speedup 1.0000x reference)
//
#include <hip/hip_runtime.h>

#define NB   4
#define SEQ  4096
#define EMB  1024
#define HS   64

// A.i += Q.i * scalar S  (component i = row)
#define FMA4(A, Q, S)                                                          \
  A.x = fmaf(Q.x, S, A.x); A.y = fmaf(Q.y, S, A.y);                            \
  A.z = fmaf(Q.z, S, A.z); A.w = fmaf(Q.w, S, A.w)

__device__ inline float4 shfl_xor4(float4 v, int m) {
  float4 r;
  r.x = __shfl_xor(v.x, m); r.y = __shfl_xor(v.y, m);
  r.z = __shfl_xor(v.z, m); r.w = __shfl_xor(v.w, m);
  return r;
}

// ---------------------------------------------------------------------------
// Kernel 0: concatenate Wq|Wk|Wv -> Wcat[192][1024] so projection waves get a
// single uniform base pointer (rows 0..63 = q, 64..127 = k, 128..191 = v).
// ---------------------------------------------------------------------------
__global__ __launch_bounds__(256) void wcat_kernel(
    const float* __restrict__ Wk, const float* __restrict__ Wq,
    const float* __restrict__ Wv, float* __restrict__ Wcat) {
  int i = blockIdx.x * 256 + threadIdx.x;  // float4 index, 192*1024/4 = 49152
  if (i < 49152) {
    int e = i >> 8;   // row 0..191
    int c = i & 255;  // float4 col
    float4 val;
    if (e < 64)       val = ((const float4*)Wq)[e * 256 + c];
    else if (e < 128) val = ((const float4*)Wk)[(e - 64) * 256 + c];
    else              val = ((const float4*)Wv)[(e - 128) * 256 + c];
    ((float4*)Wcat)[i] = val;
  }
}

// ---------------------------------------------------------------------------
// Kernel 1: QKV projection.
// 256 blocks x 256 threads (4 waves). Block = 64 rows of x. lane = row,
// wave w handles heads [48w, 48w+48) of concatenated q|k|v -> 1024 waves
// total = exactly 1 wave per SIMD, balanced.
// Outputs: qT,kT as [B][H][N] (transposed, coalesced since lane = n),
//          v  as [B][N][H] (natural).
// ---------------------------------------------------------------------------
__global__ __launch_bounds__(256) void qkv_proj(
    const float* __restrict__ x, const float* __restrict__ Wcat,
    float* __restrict__ qT, float* __restrict__ kT, float* __restrict__ v) {
  __shared__ float xs[64 * 68];  // 64 rows x 64 cols, stride 68 (bank spread)
  const int t    = threadIdx.x;
  const int lane = t & 63;   // row within tile
  const int w    = t >> 6;   // wave 0..3 -> head group
  const int m0   = blockIdx.x * 64;
  const int b    = m0 >> 12;     // /4096
  const int n0   = m0 & 4095;

  float acc[48];
#pragma unroll
  for (int j = 0; j < 48; ++j) acc[j] = 0.f;

  const int wu = __builtin_amdgcn_readfirstlane(w);  // provably wave-uniform
  const float* wbase = Wcat + wu * 48 * EMB;

  for (int k0 = 0; k0 < EMB; k0 += 64) {
    __syncthreads();  // previous chunk's reads done
#pragma unroll
    for (int i = 0; i < 4; ++i) {
      int f  = t + (i << 8);        // 0..1023 float4 slots
      int r  = f >> 4;
      int c4 = (f & 15) << 2;
      *(float4*)&xs[r * 68 + c4] =
          *(const float4*)&x[(m0 + r) * EMB + k0 + c4];
    }
    __syncthreads();
#pragma unroll 4
    for (int kk = 0; kk < 64; kk += 4) {
      float4 xv = *(const float4*)&xs[lane * 68 + kk];
#pragma unroll
      for (int j = 0; j < 48; ++j) {
        float4 wv = *(const float4*)&wbase[j * EMB + k0 + kk];
        acc[j] = fmaf(xv.x, wv.x, acc[j]);
        acc[j] = fmaf(xv.y, wv.y, acc[j]);
        acc[j] = fmaf(xv.z, wv.z, acc[j]);
        acc[j] = fmaf(xv.w, wv.w, acc[j]);
      }
    }
  }

  const int n = n0 + lane;
#pragma unroll
  for (int j = 0; j < 48; ++j) {
    int H3 = w * 48 + j;  // wave-uniform branch
    if (H3 < 64)        qT[(b * 64 + H3) * SEQ + n] = acc[j];
    else if (H3 < 128)  kT[(b * 64 + (H3 - 64)) * SEQ + n] = acc[j];
    else                v[(b * SEQ + n) * HS + (H3 - 128)] = acc[j];
  }
}

// ---------------------------------------------------------------------------
// Kernel 2: flash-style attention, fp32.
// Grid (64, 4): blockIdx.x = q-tile (64 rows), blockIdx.y = batch.
// 256 threads: tx = t&15 (key/dim group *4), ty = t>>4 (row group *4).
// Each thread: 4x4 S tile, 4x4 O tile, online softmax in log2 domain.
// LDS: Qt[h][r] 16KB, Vs[c][h] 16KB, KP = union(Kt[h][c] stride64,
//      Pt[key][row] stride 68) 17KB -> 49KB static.
// ---------------------------------------------------------------------------
__global__ __launch_bounds__(256) void attn_kernel(
    const float* __restrict__ qT, const float* __restrict__ kT,
    const float* __restrict__ vN, float* __restrict__ out) {
  __shared__ float Qt[64 * 64];
  __shared__ float Vs[64 * 64];
  __shared__ float KP[68 * 64];  // Kt (stride 64) aliased with Pt (stride 68)

  const int t  = threadIdx.x;
  const int tx = t & 15;
  const int ty = t >> 4;
  const int r0 = ty << 2;  // rows r0..r0+3
  const int c0 = tx << 2;  // keys/dims c0..c0+3
  const int b  = blockIdx.y;
  const int q0 = blockIdx.x << 6;

  // Q tile: Qt[h][r] <- qT[b][h][q0+r]  (straight float4 copy)
#pragma unroll
  for (int i = 0; i < 4; ++i) {
    int f = t + (i << 8);
    int h = f >> 4, r4 = (f & 15) << 2;
    *(float4*)&Qt[h * 64 + r4] =
        *(const float4*)&qT[((b << 6) + h) * SEQ + q0 + r4];
  }

  float4 m4 = make_float4(-1e30f, -1e30f, -1e30f, -1e30f);  // comps = rows
  float4 l4 = make_float4(0.f, 0.f, 0.f, 0.f);
  float4 O0 = {0,0,0,0}, O1 = {0,0,0,0}, O2 = {0,0,0,0}, O3 = {0,0,0,0};

  const float cs = 0.18033688011112042f;  // (1/sqrt(64)) * log2(e)

  for (int k0 = 0; k0 < SEQ; k0 += 64) {
    __syncthreads();  // prev iter's Pt reads / Vs reads done
#pragma unroll
    for (int i = 0; i < 4; ++i) {
      int f = t + (i << 8);
      int a = f >> 4, d4 = (f & 15) << 2;
      *(float4*)&KP[a * 64 + d4] =
          *(const float4*)&kT[((b << 6) + a) * SEQ + k0 + d4];
      *(float4*)&Vs[a * 64 + d4] =
          *(const float4*)&vN[(b * SEQ + k0 + a) * HS + d4];
    }
    __syncthreads();

    // S = Q K^T : s{j}.i = S[r0+i][c0+j]
    float4 s0 = {0,0,0,0}, s1 = {0,0,0,0}, s2 = {0,0,0,0}, s3 = {0,0,0,0};
#pragma unroll 8
    for (int kk = 0; kk < 64; ++kk) {
      float4 qv = *(const float4*)&Qt[kk * 64 + r0];  // broadcast over tx
      float4 kv = *(const float4*)&KP[kk * 64 + c0];  // 2-way, free
      FMA4(s0, qv, kv.x);
      FMA4(s1, qv, kv.y);
      FMA4(s2, qv, kv.z);
      FMA4(s3, qv, kv.w);
    }
    __syncthreads();  // everyone done reading Kt before Pt overwrite

    // scale into log2 domain
    s0.x *= cs; s0.y *= cs; s0.z *= cs; s0.w *= cs;
    s1.x *= cs; s1.y *= cs; s1.z *= cs; s1.w *= cs;
    s2.x *= cs; s2.y *= cs; s2.z *= cs; s2.w *= cs;
    s3.x *= cs; s3.y *= cs; s3.z *= cs; s3.w *= cs;

    // tile row-max (over j regs, then over tx lanes)
    float4 rm;
    rm.x = fmaxf(fmaxf(s0.x, s1.x), fmaxf(s2.x, s3.x));
    rm.y = fmaxf(fmaxf(s0.y, s1.y), fmaxf(s2.y, s3.y));
    rm.z = fmaxf(fmaxf(s0.z, s1.z), fmaxf(s2.z, s3.z));
    rm.w = fmaxf(fmaxf(s0.w, s1.w), fmaxf(s2.w, s3.w));
#pragma unroll
    for (int off = 1; off < 16; off <<= 1) {
      float4 o = shfl_xor4(rm, off);
      rm.x = fmaxf(rm.x, o.x); rm.y = fmaxf(rm.y, o.y);
      rm.z = fmaxf(rm.z, o.z); rm.w = fmaxf(rm.w, o.w);
    }
    float4 mn;
    mn.x = fmaxf(m4.x, rm.x); mn.y = fmaxf(m4.y, rm.y);
    mn.z = fmaxf(m4.z, rm.z); mn.w = fmaxf(m4.w, rm.w);
    float4 al;
    al.x = exp2f(m4.x - mn.x); al.y = exp2f(m4.y - mn.y);
    al.z = exp2f(m4.z - mn.z); al.w = exp2f(m4.w - mn.w);
    // P = exp2(S - m), in place
    s0.x = exp2f(s0.x - mn.x); s0.y = exp2f(s0.y - mn.y);
    s0.z = exp2f(s0.z - mn.z); s0.w = exp2f(s0.w - mn.w);
    s1.x = exp2f(s1.x - mn.x); s1.y = exp2f(s1.y - mn.y);
    s1.z = exp2f(s1.z - mn.z); s1.w = exp2f(s1.w - mn.w);
    s2.x = exp2f(s2.x - mn.x); s2.y = exp2f(s2.y - mn.y);
    s2.z = exp2f(s2.z - mn.z); s2.w = exp2f(s2.w - mn.w);
    s3.x = exp2f(s3.x - mn.x); s3.y = exp2f(s3.y - mn.y);
    s3.z = exp2f(s3.z - mn.z); s3.w = exp2f(s3.w - mn.w);
    // tile row-sum
    float4 rs;
    rs.x = s0.x + s1.x + s2.x + s3.x;
    rs.y = s0.y + s1.y + s2.y + s3.y;
    rs.z = s0.z + s1.z + s2.z + s3.z;
    rs.w = s0.w + s1.w + s2.w + s3.w;
#pragma unroll
    for (int off = 1; off < 16; off <<= 1) {
      float4 o = shfl_xor4(rs, off);
      rs.x += o.x; rs.y += o.y; rs.z += o.z; rs.w += o.w;
    }
    l4.x = l4.x * al.x + rs.x; l4.y = l4.y * al.y + rs.y;
    l4.z = l4.z * al.z + rs.z; l4.w = l4.w * al.w + rs.w;
    m4 = mn;
    // rescale O by alpha (per row = per component)
    O0.x *= al.x; O0.y *= al.y; O0.z *= al.z; O0.w *= al.w;
    O1.x *= al.x; O1.y *= al.y; O1.z *= al.z; O1.w *= al.w;
    O2.x *= al.x; O2.y *= al.y; O2.z *= al.z; O2.w *= al.w;
    O3.x *= al.x; O3.y *= al.y; O3.z *= al.z; O3.w *= al.w;

    // write Pt[key][row] (stride 68, 16B aligned)
    *(float4*)&KP[(c0 + 0) * 68 + r0] = s0;
    *(float4*)&KP[(c0 + 1) * 68 + r0] = s1;
    *(float4*)&KP[(c0 + 2) * 68 + r0] = s2;
    *(float4*)&KP[(c0 + 3) * 68 + r0] = s3;
    __syncthreads();

    // O += P V
#pragma unroll 4
    for (int k = 0; k < 64; k += 4) {
      float4 pa = *(const float4*)&KP[(k + 0) * 68 + r0];
      float4 pb = *(const float4*)&KP[(k + 1) * 68 + r0];
      float4 pc = *(const float4*)&KP[(k + 2) * 68 + r0];
      float4 pd = *(const float4*)&KP[(k + 3) * 68 + r0];
      float4 va = *(const float4*)&Vs[(k + 0) * 64 + c0];
      float4 vb = *(const float4*)&Vs[(k + 1) * 64 + c0];
      float4 vc = *(const float4*)&Vs[(k + 2) * 64 + c0];
      float4 vd = *(const float4*)&Vs[(k + 3) * 64 + c0];
      FMA4(O0, pa, va.x); FMA4(O1, pa, va.y); FMA4(O2, pa, va.z); FMA4(O3, pa, va.w);
      FMA4(O0, pb, vb.x); FMA4(O1, pb, vb.y); FMA4(O2, pb, vb.z); FMA4(O3, pb, vb.w);
      FMA4(O0, pc, vc.x); FMA4(O1, pc, vc.y); FMA4(O2, pc, vc.z); FMA4(O3, pc, vc.w);
      FMA4(O0, pd, vd.x); FMA4(O1, pd, vd.y); FMA4(O2, pd, vd.z); FMA4(O3, pd, vd.w);
    }
  }

  // finalize: divide by l, store rows (comps of O regs are rows)
  float4 il;
  il.x = 1.f / l4.x; il.y = 1.f / l4.y; il.z = 1.f / l4.z; il.w = 1.f / l4.w;
  O0.x *= il.x; O0.y *= il.y; O0.z *= il.z; O0.w *= il.w;
  O1.x *= il.x; O1.y *= il.y; O1.z *= il.z; O1.w *= il.w;
  O2.x *= il.x; O2.y *= il.y; O2.z *= il.z; O2.w *= il.w;
  O3.x *= il.x; O3.y *= il.y; O3.z *= il.z; O3.w *= il.w;

  float4 row;
  row.x = O0.x; row.y = O1.x; row.z = O2.x; row.w = O3.x;
  *(float4*)&out[(b * SEQ + q0 + r0 + 0) * HS + c0] = row;
  row.x = O0.y; row.y = O1.y; row.z = O2.y; row.w = O3.y;
  *(float4*)&out[(b * SEQ + q0 + r0 + 1) * HS + c0] = row;
  row.x = O0.z; row.y = O1.z; row.z = O2.z; row.w = O3.z;
  *(float4*)&out[(b * SEQ + q0 + r0 + 2) * HS + c0] = row;
  row.x = O0.w; row.y = O1.w; row.z = O2.w; row.w = O3.w;
  *(float4*)&out[(b * SEQ + q0 + r0 + 3) * HS + c0] = row;
}

// ---------------------------------------------------------------------------
extern "C" void kernel_launch(void* const* d_in, const int* in_sizes, int n_in,
                              void* d_out, int out_size, void* d_ws,
                              size_t ws_size, hipStream_t stream) {
  const float* x  = (const float*)d_in[0];
  const float* Wk = (const float*)d_in[1];
  const float* Wq = (const float*)d_in[2];
  const float* Wv = (const float*)d_in[3];
  float* out = (float*)d_out;

  float* ws   = (float*)d_ws;
  float* qT   = ws;                  // [B][H][N]  1M floats
  float* kT   = ws + (1 << 20);      // [B][H][N]  1M floats
  float* vv   = ws + (2 << 20);      // [B][N][H]  1M floats
  float* Wcat = ws + (3 << 20);      // [192][1024] 192K floats

  wcat_kernel<<<192, 256, 0, stream>>>(Wk, Wq, Wv, Wcat);
  qkv_proj<<<256, 256, 0, stream>>>(x, Wcat, qT, kT, vv);
  attn_kernel<<<dim3(64, NB), 256, 0, stream>>>(qT, kT, vv, out);
}

// Round 2
// 520.906 us; speedup vs baseline: 2.5274x; 2.5274x over previous
//
#include <hip/hip_runtime.h>

#define NB   4
#define SEQ  4096
#define EMB  1024
#define HS   64

// A.i += Q.i * scalar S
#define FMA4(A, Q, S)                                                          \
  A.x = fmaf(Q.x, S, A.x); A.y = fmaf(Q.y, S, A.y);                            \
  A.z = fmaf(Q.z, S, A.z); A.w = fmaf(Q.w, S, A.w)

__device__ inline float4 shfl_xor4(float4 v, int m) {
  float4 r;
  r.x = __shfl_xor(v.x, m); r.y = __shfl_xor(v.y, m);
  r.z = __shfl_xor(v.z, m); r.w = __shfl_xor(v.w, m);
  return r;
}

// ---------------------------------------------------------------------------
// QKV projection as tiled GEMM: C[16384 x 192] = x[16384 x 1024] . W^T.
// Grid (256, 3): blockIdx.x = 64-row m-tile, blockIdx.y selects Wq/Wk/Wv.
// 256 threads, TM=TN=4, BK=32, LDS-staged x and W (transposed [k][row]),
// register prefetch of next stage's global loads.
// Outputs: qT,kT as [B][H][N] (what attn_kernel consumes), v as [B][N][H].
// ---------------------------------------------------------------------------
__global__ __launch_bounds__(256) void qkv_proj(
    const float* __restrict__ x,  const float* __restrict__ Wq,
    const float* __restrict__ Wk, const float* __restrict__ Wv,
    float* __restrict__ qT, float* __restrict__ kT, float* __restrict__ v) {
  __shared__ float xs[32 * 68];  // [k][m], stride 68
  __shared__ float ws[32 * 68];  // [k][n], stride 68

  const int t  = threadIdx.x;
  const int tx = t & 15;        // -> 4 output cols (heads)
  const int ty = t >> 4;        // -> 4 output rows (seq)
  const int m0 = blockIdx.x * 64;
  const int b  = m0 >> 12;
  const int n0 = m0 & 4095;
  const int gy = blockIdx.y;    // 0=q, 1=k, 2=v
  const float* __restrict__ W = (gy == 0) ? Wq : (gy == 1) ? Wk : Wv;

  // load lane mapping: 8 lanes x 16B cover one row's 32-float chunk
  const int r0 = t >> 3;        // 0..31
  const int k4 = (t & 7) << 2;  // 0,4,...,28

  // prefetch stage 0
  float4 px0 = *(const float4*)&x[(m0 + r0) * EMB + k4];
  float4 px1 = *(const float4*)&x[(m0 + r0 + 32) * EMB + k4];
  float4 pw0 = *(const float4*)&W[r0 * EMB + k4];
  float4 pw1 = *(const float4*)&W[(r0 + 32) * EMB + k4];

  float4 acc0 = {0,0,0,0}, acc1 = {0,0,0,0}, acc2 = {0,0,0,0}, acc3 = {0,0,0,0};

  for (int s = 0; s < 32; ++s) {
    __syncthreads();  // previous stage's reads done
    // transposed LDS writes (4-way bank alias on writes; small vs compute)
    xs[(k4 + 0) * 68 + r0] = px0.x;
    xs[(k4 + 1) * 68 + r0] = px0.y;
    xs[(k4 + 2) * 68 + r0] = px0.z;
    xs[(k4 + 3) * 68 + r0] = px0.w;
    xs[(k4 + 0) * 68 + r0 + 32] = px1.x;
    xs[(k4 + 1) * 68 + r0 + 32] = px1.y;
    xs[(k4 + 2) * 68 + r0 + 32] = px1.z;
    xs[(k4 + 3) * 68 + r0 + 32] = px1.w;
    ws[(k4 + 0) * 68 + r0] = pw0.x;
    ws[(k4 + 1) * 68 + r0] = pw0.y;
    ws[(k4 + 2) * 68 + r0] = pw0.z;
    ws[(k4 + 3) * 68 + r0] = pw0.w;
    ws[(k4 + 0) * 68 + r0 + 32] = pw1.x;
    ws[(k4 + 1) * 68 + r0 + 32] = pw1.y;
    ws[(k4 + 2) * 68 + r0 + 32] = pw1.z;
    ws[(k4 + 3) * 68 + r0 + 32] = pw1.w;
    __syncthreads();

    if (s < 31) {  // issue next stage's globals; they fly during compute
      const int ko = (s + 1) * 32 + k4;
      px0 = *(const float4*)&x[(m0 + r0) * EMB + ko];
      px1 = *(const float4*)&x[(m0 + r0 + 32) * EMB + ko];
      pw0 = *(const float4*)&W[r0 * EMB + ko];
      pw1 = *(const float4*)&W[(r0 + 32) * EMB + ko];
    }

#pragma unroll 8
    for (int kk = 0; kk < 32; ++kk) {
      float4 a  = *(const float4*)&xs[kk * 68 + ty * 4];  // 4-val broadcast
      float4 w4 = *(const float4*)&ws[kk * 68 + tx * 4];  // 2-way, free
      FMA4(acc0, w4, a.x);
      FMA4(acc1, w4, a.y);
      FMA4(acc2, w4, a.z);
      FMA4(acc3, w4, a.w);
    }
  }

  if (gy == 2) {
    // v natural [B][N][H]: row r -> float4 over 4 heads
    *(float4*)&v[(b * SEQ + n0 + ty * 4 + 0) * HS + tx * 4] = acc0;
    *(float4*)&v[(b * SEQ + n0 + ty * 4 + 1) * HS + tx * 4] = acc1;
    *(float4*)&v[(b * SEQ + n0 + ty * 4 + 2) * HS + tx * 4] = acc2;
    *(float4*)&v[(b * SEQ + n0 + ty * 4 + 3) * HS + tx * 4] = acc3;
  } else {
    float* __restrict__ o = (gy == 0) ? qT : kT;
    // transposed [B][H][N]: per head h, 4 consecutive seq positions
#pragma unroll
    for (int c = 0; c < 4; ++c) {
      float4 col;
      col.x = (c == 0) ? acc0.x : (c == 1) ? acc0.y : (c == 2) ? acc0.z : acc0.w;
      col.y = (c == 0) ? acc1.x : (c == 1) ? acc1.y : (c == 2) ? acc1.z : acc1.w;
      col.z = (c == 0) ? acc2.x : (c == 1) ? acc2.y : (c == 2) ? acc2.z : acc2.w;
      col.w = (c == 0) ? acc3.x : (c == 1) ? acc3.y : (c == 2) ? acc3.z : acc3.w;
      *(float4*)&o[((b << 6) + tx * 4 + c) * SEQ + n0 + ty * 4] = col;
    }
  }
}

// ---------------------------------------------------------------------------
// Kernel 2: flash-style attention, fp32 (unchanged from round 1).
// ---------------------------------------------------------------------------
__global__ __launch_bounds__(256) void attn_kernel(
    const float* __restrict__ qT, const float* __restrict__ kT,
    const float* __restrict__ vN, float* __restrict__ out) {
  __shared__ float Qt[64 * 64];
  __shared__ float Vs[64 * 64];
  __shared__ float KP[68 * 64];  // Kt (stride 64) aliased with Pt (stride 68)

  const int t  = threadIdx.x;
  const int tx = t & 15;
  const int ty = t >> 4;
  const int r0 = ty << 2;
  const int c0 = tx << 2;
  const int b  = blockIdx.y;
  const int q0 = blockIdx.x << 6;

#pragma unroll
  for (int i = 0; i < 4; ++i) {
    int f = t + (i << 8);
    int h = f >> 4, r4 = (f & 15) << 2;
    *(float4*)&Qt[h * 64 + r4] =
        *(const float4*)&qT[((b << 6) + h) * SEQ + q0 + r4];
  }

  float4 m4 = make_float4(-1e30f, -1e30f, -1e30f, -1e30f);
  float4 l4 = make_float4(0.f, 0.f, 0.f, 0.f);
  float4 O0 = {0,0,0,0}, O1 = {0,0,0,0}, O2 = {0,0,0,0}, O3 = {0,0,0,0};

  const float cs = 0.18033688011112042f;  // (1/sqrt(64)) * log2(e)

  for (int k0 = 0; k0 < SEQ; k0 += 64) {
    __syncthreads();
#pragma unroll
    for (int i = 0; i < 4; ++i) {
      int f = t + (i << 8);
      int a = f >> 4, d4 = (f & 15) << 2;
      *(float4*)&KP[a * 64 + d4] =
          *(const float4*)&kT[((b << 6) + a) * SEQ + k0 + d4];
      *(float4*)&Vs[a * 64 + d4] =
          *(const float4*)&vN[(b * SEQ + k0 + a) * HS + d4];
    }
    __syncthreads();

    float4 s0 = {0,0,0,0}, s1 = {0,0,0,0}, s2 = {0,0,0,0}, s3 = {0,0,0,0};
#pragma unroll 8
    for (int kk = 0; kk < 64; ++kk) {
      float4 qv = *(const float4*)&Qt[kk * 64 + r0];
      float4 kv = *(const float4*)&KP[kk * 64 + c0];
      FMA4(s0, qv, kv.x);
      FMA4(s1, qv, kv.y);
      FMA4(s2, qv, kv.z);
      FMA4(s3, qv, kv.w);
    }
    __syncthreads();

    s0.x *= cs; s0.y *= cs; s0.z *= cs; s0.w *= cs;
    s1.x *= cs; s1.y *= cs; s1.z *= cs; s1.w *= cs;
    s2.x *= cs; s2.y *= cs; s2.z *= cs; s2.w *= cs;
    s3.x *= cs; s3.y *= cs; s3.z *= cs; s3.w *= cs;

    float4 rm;
    rm.x = fmaxf(fmaxf(s0.x, s1.x), fmaxf(s2.x, s3.x));
    rm.y = fmaxf(fmaxf(s0.y, s1.y), fmaxf(s2.y, s3.y));
    rm.z = fmaxf(fmaxf(s0.z, s1.z), fmaxf(s2.z, s3.z));
    rm.w = fmaxf(fmaxf(s0.w, s1.w), fmaxf(s2.w, s3.w));
#pragma unroll
    for (int off = 1; off < 16; off <<= 1) {
      float4 o = shfl_xor4(rm, off);
      rm.x = fmaxf(rm.x, o.x); rm.y = fmaxf(rm.y, o.y);
      rm.z = fmaxf(rm.z, o.z); rm.w = fmaxf(rm.w, o.w);
    }
    float4 mn;
    mn.x = fmaxf(m4.x, rm.x); mn.y = fmaxf(m4.y, rm.y);
    mn.z = fmaxf(m4.z, rm.z); mn.w = fmaxf(m4.w, rm.w);
    float4 al;
    al.x = exp2f(m4.x - mn.x); al.y = exp2f(m4.y - mn.y);
    al.z = exp2f(m4.z - mn.z); al.w = exp2f(m4.w - mn.w);
    s0.x = exp2f(s0.x - mn.x); s0.y = exp2f(s0.y - mn.y);
    s0.z = exp2f(s0.z - mn.z); s0.w = exp2f(s0.w - mn.w);
    s1.x = exp2f(s1.x - mn.x); s1.y = exp2f(s1.y - mn.y);
    s1.z = exp2f(s1.z - mn.z); s1.w = exp2f(s1.w - mn.w);
    s2.x = exp2f(s2.x - mn.x); s2.y = exp2f(s2.y - mn.y);
    s2.z = exp2f(s2.z - mn.z); s2.w = exp2f(s2.w - mn.w);
    s3.x = exp2f(s3.x - mn.x); s3.y = exp2f(s3.y - mn.y);
    s3.z = exp2f(s3.z - mn.z); s3.w = exp2f(s3.w - mn.w);
    float4 rs;
    rs.x = s0.x + s1.x + s2.x + s3.x;
    rs.y = s0.y + s1.y + s2.y + s3.y;
    rs.z = s0.z + s1.z + s2.z + s3.z;
    rs.w = s0.w + s1.w + s2.w + s3.w;
#pragma unroll
    for (int off = 1; off < 16; off <<= 1) {
      float4 o = shfl_xor4(rs, off);
      rs.x += o.x; rs.y += o.y; rs.z += o.z; rs.w += o.w;
    }
    l4.x = l4.x * al.x + rs.x; l4.y = l4.y * al.y + rs.y;
    l4.z = l4.z * al.z + rs.z; l4.w = l4.w * al.w + rs.w;
    m4 = mn;
    O0.x *= al.x; O0.y *= al.y; O0.z *= al.z; O0.w *= al.w;
    O1.x *= al.x; O1.y *= al.y; O1.z *= al.z; O1.w *= al.w;
    O2.x *= al.x; O2.y *= al.y; O2.z *= al.z; O2.w *= al.w;
    O3.x *= al.x; O3.y *= al.y; O3.z *= al.z; O3.w *= al.w;

    *(float4*)&KP[(c0 + 0) * 68 + r0] = s0;
    *(float4*)&KP[(c0 + 1) * 68 + r0] = s1;
    *(float4*)&KP[(c0 + 2) * 68 + r0] = s2;
    *(float4*)&KP[(c0 + 3) * 68 + r0] = s3;
    __syncthreads();

#pragma unroll 4
    for (int k = 0; k < 64; k += 4) {
      float4 pa = *(const float4*)&KP[(k + 0) * 68 + r0];
      float4 pb = *(const float4*)&KP[(k + 1) * 68 + r0];
      float4 pc = *(const float4*)&KP[(k + 2) * 68 + r0];
      float4 pd = *(const float4*)&KP[(k + 3) * 68 + r0];
      float4 va = *(const float4*)&Vs[(k + 0) * 64 + c0];
      float4 vb = *(const float4*)&Vs[(k + 1) * 64 + c0];
      float4 vc = *(const float4*)&Vs[(k + 2) * 64 + c0];
      float4 vd = *(const float4*)&Vs[(k + 3) * 64 + c0];
      FMA4(O0, pa, va.x); FMA4(O1, pa, va.y); FMA4(O2, pa, va.z); FMA4(O3, pa, va.w);
      FMA4(O0, pb, vb.x); FMA4(O1, pb, vb.y); FMA4(O2, pb, vb.z); FMA4(O3, pb, vb.w);
      FMA4(O0, pc, vc.x); FMA4(O1, pc, vc.y); FMA4(O2, pc, vc.z); FMA4(O3, pc, vc.w);
      FMA4(O0, pd, vd.x); FMA4(O1, pd, vd.y); FMA4(O2, pd, vd.z); FMA4(O3, pd, vd.w);
    }
  }

  float4 il;
  il.x = 1.f / l4.x; il.y = 1.f / l4.y; il.z = 1.f / l4.z; il.w = 1.f / l4.w;
  O0.x *= il.x; O0.y *= il.y; O0.z *= il.z; O0.w *= il.w;
  O1.x *= il.x; O1.y *= il.y; O1.z *= il.z; O1.w *= il.w;
  O2.x *= il.x; O2.y *= il.y; O2.z *= il.z; O2.w *= il.w;
  O3.x *= il.x; O3.y *= il.y; O3.z *= il.z; O3.w *= il.w;

  float4 row;
  row.x = O0.x; row.y = O1.x; row.z = O2.x; row.w = O3.x;
  *(float4*)&out[(b * SEQ + q0 + r0 + 0) * HS + c0] = row;
  row.x = O0.y; row.y = O1.y; row.z = O2.y; row.w = O3.y;
  *(float4*)&out[(b * SEQ + q0 + r0 + 1) * HS + c0] = row;
  row.x = O0.z; row.y = O1.z; row.z = O2.z; row.w = O3.z;
  *(float4*)&out[(b * SEQ + q0 + r0 + 2) * HS + c0] = row;
  row.x = O0.w; row.y = O1.w; row.z = O2.w; row.w = O3.w;
  *(float4*)&out[(b * SEQ + q0 + r0 + 3) * HS + c0] = row;
}

// ---------------------------------------------------------------------------
extern "C" void kernel_launch(void* const* d_in, const int* in_sizes, int n_in,
                              void* d_out, int out_size, void* d_ws,
                              size_t ws_size, hipStream_t stream) {
  const float* x  = (const float*)d_in[0];
  const float* Wk = (const float*)d_in[1];
  const float* Wq = (const float*)d_in[2];
  const float* Wv = (const float*)d_in[3];
  float* out = (float*)d_out;

  float* ws = (float*)d_ws;
  float* qT = ws;              // [B][H][N]  1M floats
  float* kT = ws + (1 << 20);  // [B][H][N]  1M floats
  float* vv = ws + (2 << 20);  // [B][N][H]  1M floats

  qkv_proj<<<dim3(256, 3), 256, 0, stream>>>(x, Wq, Wk, Wv, qT, kT, vv);
  attn_kernel<<<dim3(64, NB), 256, 0, stream>>>(qT, kT, vv, out);
}

// Round 3
// 287.841 us; speedup vs baseline: 4.5739x; 1.8097x over previous
//
#include <hip/hip_runtime.h>
#include <math.h>

#define NB   4
#define SEQ  4096
#define EMB  1024
#define HS   64

typedef __attribute__((ext_vector_type(8))) short bf16x8;   // 8 bf16 = 4 VGPRs
typedef __attribute__((ext_vector_type(4))) float f32x4;    // MFMA C/D

// A.i += Q.i * scalar S
#define FMA4(A, Q, S)                                                          \
  A.x = fmaf(Q.x, S, A.x); A.y = fmaf(Q.y, S, A.y);                            \
  A.z = fmaf(Q.z, S, A.z); A.w = fmaf(Q.w, S, A.w)

__device__ inline unsigned short f2bf(float f) {  // fp32 -> bf16 RNE
  unsigned int u = __float_as_uint(f);
  u += 0x7fffu + ((u >> 16) & 1u);
  return (unsigned short)(u >> 16);
}
__device__ inline float bf2f(unsigned short h) {
  return __uint_as_float(((unsigned int)h) << 16);
}
__device__ inline float fcomp(const float4& v, int i) {
  return i == 0 ? v.x : i == 1 ? v.y : i == 2 ? v.z : v.w;
}
// ushort index of 16B chunk (row, c) in a 64x64 bf16 LDS tile, XOR-swizzled
// so b128 frag reads (16 lanes = 16 rows, same c) are bank-conflict-free.
__device__ inline int swzi(int row, int c) {
  return row * 64 + ((c ^ (row & 7)) << 3);
}

// ---------------------------------------------------------------------------
// QKV projection: fp32 tiled GEMM core (round-2), new bf16 epilogue.
// gy=0: Q*scale*log2e  -> qh,ql [B][N][H] bf16 hi/lo
// gy=1: K              -> kh,kl [B][N][H] bf16 hi/lo
// gy=2: V              -> vt    [B][H][N] bf16
// ---------------------------------------------------------------------------
__global__ __launch_bounds__(256) void qkv_proj(
    const float* __restrict__ x,  const float* __restrict__ Wq,
    const float* __restrict__ Wk, const float* __restrict__ Wv,
    unsigned short* __restrict__ qh, unsigned short* __restrict__ ql,
    unsigned short* __restrict__ kh, unsigned short* __restrict__ kl,
    unsigned short* __restrict__ vt) {
  __shared__ float xs[32 * 68];
  __shared__ float ws[32 * 68];

  const int t  = threadIdx.x;
  const int tx = t & 15;
  const int ty = t >> 4;
  const int m0 = blockIdx.x * 64;
  const int b  = m0 >> 12;
  const int n0 = m0 & 4095;
  const int gy = blockIdx.y;  // 0=q, 1=k, 2=v
  const float* __restrict__ W = (gy == 0) ? Wq : (gy == 1) ? Wk : Wv;

  const int r0 = t >> 3;
  const int k4 = (t & 7) << 2;

  float4 px0 = *(const float4*)&x[(m0 + r0) * EMB + k4];
  float4 px1 = *(const float4*)&x[(m0 + r0 + 32) * EMB + k4];
  float4 pw0 = *(const float4*)&W[r0 * EMB + k4];
  float4 pw1 = *(const float4*)&W[(r0 + 32) * EMB + k4];

  float4 acc0 = {0,0,0,0}, acc1 = {0,0,0,0}, acc2 = {0,0,0,0}, acc3 = {0,0,0,0};

  for (int s = 0; s < 32; ++s) {
    __syncthreads();
    xs[(k4 + 0) * 68 + r0] = px0.x;
    xs[(k4 + 1) * 68 + r0] = px0.y;
    xs[(k4 + 2) * 68 + r0] = px0.z;
    xs[(k4 + 3) * 68 + r0] = px0.w;
    xs[(k4 + 0) * 68 + r0 + 32] = px1.x;
    xs[(k4 + 1) * 68 + r0 + 32] = px1.y;
    xs[(k4 + 2) * 68 + r0 + 32] = px1.z;
    xs[(k4 + 3) * 68 + r0 + 32] = px1.w;
    ws[(k4 + 0) * 68 + r0] = pw0.x;
    ws[(k4 + 1) * 68 + r0] = pw0.y;
    ws[(k4 + 2) * 68 + r0] = pw0.z;
    ws[(k4 + 3) * 68 + r0] = pw0.w;
    ws[(k4 + 0) * 68 + r0 + 32] = pw1.x;
    ws[(k4 + 1) * 68 + r0 + 32] = pw1.y;
    ws[(k4 + 2) * 68 + r0 + 32] = pw1.z;
    ws[(k4 + 3) * 68 + r0 + 32] = pw1.w;
    __syncthreads();

    if (s < 31) {
      const int ko = (s + 1) * 32 + k4;
      px0 = *(const float4*)&x[(m0 + r0) * EMB + ko];
      px1 = *(const float4*)&x[(m0 + r0 + 32) * EMB + ko];
      pw0 = *(const float4*)&W[r0 * EMB + ko];
      pw1 = *(const float4*)&W[(r0 + 32) * EMB + ko];
    }

#pragma unroll 8
    for (int kk = 0; kk < 32; ++kk) {
      float4 a  = *(const float4*)&xs[kk * 68 + ty * 4];
      float4 w4 = *(const float4*)&ws[kk * 68 + tx * 4];
      FMA4(acc0, w4, a.x);
      FMA4(acc1, w4, a.y);
      FMA4(acc2, w4, a.z);
      FMA4(acc3, w4, a.w);
    }
  }

  float4 a4[4] = {acc0, acc1, acc2, acc3};
  if (gy == 0) {
    const float csq = 0.18033688011112042f;  // (1/sqrt(64)) * log2(e)
#pragma unroll
    for (int r = 0; r < 4; ++r) {
      a4[r].x *= csq; a4[r].y *= csq; a4[r].z *= csq; a4[r].w *= csq;
    }
  }

  if (gy != 2) {
    unsigned short* __restrict__ oh = (gy == 0) ? qh : kh;
    unsigned short* __restrict__ ol = (gy == 0) ? ql : kl;
#pragma unroll
    for (int r = 0; r < 4; ++r) {
      ushort4 hv, lv;
      hv.x = f2bf(a4[r].x); lv.x = f2bf(a4[r].x - bf2f(hv.x));
      hv.y = f2bf(a4[r].y); lv.y = f2bf(a4[r].y - bf2f(hv.y));
      hv.z = f2bf(a4[r].z); lv.z = f2bf(a4[r].z - bf2f(hv.z));
      hv.w = f2bf(a4[r].w); lv.w = f2bf(a4[r].w - bf2f(hv.w));
      const int off = (b * SEQ + n0 + ty * 4 + r) * HS + tx * 4;
      *(ushort4*)&oh[off] = hv;
      *(ushort4*)&ol[off] = lv;
    }
  } else {
#pragma unroll
    for (int c = 0; c < 4; ++c) {
      ushort4 hv;
      hv.x = f2bf(fcomp(a4[0], c));
      hv.y = f2bf(fcomp(a4[1], c));
      hv.z = f2bf(fcomp(a4[2], c));
      hv.w = f2bf(fcomp(a4[3], c));
      *(ushort4*)&vt[(b * HS + tx * 4 + c) * SEQ + n0 + ty * 4] = hv;
    }
  }
}

// ---------------------------------------------------------------------------
// Flash attention on MFMA 16x16x32 bf16.
// Grid (64, NB), 256 thr = 4 waves. Wave w owns q-cols [16w,16w+16).
// S^T = K.Q^T (M=key, N=q): split-bf16, 3 MFMAs per frag pair.
// Online softmax in log2 domain (scale*log2e pre-folded into Q).
// P^T -> LDS (wave-local rows) -> A-operand of O += P^T.V (plain bf16).
// LDS tiles 64x64 bf16, XOR-swizzled 16B chunks; K/V register-prefetched.
// ---------------------------------------------------------------------------
__global__ __launch_bounds__(256) void attn_mfma(
    const unsigned short* __restrict__ qh, const unsigned short* __restrict__ ql,
    const unsigned short* __restrict__ kh, const unsigned short* __restrict__ kl,
    const unsigned short* __restrict__ vt, float* __restrict__ out) {
  __shared__ unsigned short KhS[4096];
  __shared__ unsigned short KlS[4096];
  __shared__ unsigned short VtS[4096];
  __shared__ unsigned short PtS[4096];

  const int t  = threadIdx.x;
  const int l  = t & 63;
  const int w  = t >> 6;   // wave id -> q-block
  const int li = l & 15;
  const int g  = l >> 4;   // quad
  const int b  = blockIdx.y;
  const int q0 = blockIdx.x << 6;

  // Persistent Q fragments (B-operand): element B[k=h][n=q], n=li, k=g*8+j.
  bf16x8 qfh[2], qfl[2];
  {
    const unsigned short* qrh = qh + (b * SEQ + q0 + 16 * w + li) * HS;
    const unsigned short* qrl = ql + (b * SEQ + q0 + 16 * w + li) * HS;
    qfh[0] = *(const bf16x8*)&qrh[g * 8];
    qfh[1] = *(const bf16x8*)&qrh[32 + g * 8];
    qfl[0] = *(const bf16x8*)&qrl[g * 8];
    qfl[1] = *(const bf16x8*)&qrl[32 + g * 8];
  }

  // Staging map: thread t handles chunks (row=t>>3, c=t&7) and (row+32, c).
  const int sr = t >> 3;
  const int sc = t & 7;
  const int wA = swzi(sr, sc);
  const int wB = swzi(sr + 32, sc);
  const unsigned short* kh_b = kh + (b * SEQ + sr) * HS + sc * 8;
  const unsigned short* kl_b = kl + (b * SEQ + sr) * HS + sc * 8;
  const unsigned short* vt_b = vt + (b * HS + sr) * SEQ + sc * 8;

  int4 pk0 = *(const int4*)(kh_b);
  int4 pk1 = *(const int4*)(kh_b + 32 * HS);
  int4 pl0 = *(const int4*)(kl_b);
  int4 pl1 = *(const int4*)(kl_b + 32 * HS);
  int4 pv0 = *(const int4*)(vt_b);
  int4 pv1 = *(const int4*)(vt_b + 32 * SEQ);

  float m = -1e30f, lsum = 0.f;
  f32x4 O[4];
  O[0] = (f32x4){0.f, 0.f, 0.f, 0.f};
  O[1] = (f32x4){0.f, 0.f, 0.f, 0.f};
  O[2] = (f32x4){0.f, 0.f, 0.f, 0.f};
  O[3] = (f32x4){0.f, 0.f, 0.f, 0.f};

  const int prow = 16 * w + li;  // P^T row this lane owns (wave-local)

  for (int it = 0; it < 64; ++it) {
    __syncthreads();  // prev iter done reading K/V LDS
    *(int4*)&KhS[wA] = pk0; *(int4*)&KhS[wB] = pk1;
    *(int4*)&KlS[wA] = pl0; *(int4*)&KlS[wB] = pl1;
    *(int4*)&VtS[wA] = pv0; *(int4*)&VtS[wB] = pv1;
    __syncthreads();

    {  // prefetch next key-tile (wraps; loads fly during compute)
      const int nk0 = ((it + 1) & 63) << 6;
      pk0 = *(const int4*)(kh_b + nk0 * HS);
      pk1 = *(const int4*)(kh_b + (nk0 + 32) * HS);
      pl0 = *(const int4*)(kl_b + nk0 * HS);
      pl1 = *(const int4*)(kl_b + (nk0 + 32) * HS);
      pv0 = *(const int4*)(vt_b + nk0);
      pv1 = *(const int4*)(vt_b + 32 * SEQ + nk0);
    }

    // S^T[key][q], 4 key-tiles of 16. Lane holds keys 16tt+4g+r, q=16w+li.
    f32x4 S[4];
    S[0] = (f32x4){0.f, 0.f, 0.f, 0.f};
    S[1] = (f32x4){0.f, 0.f, 0.f, 0.f};
    S[2] = (f32x4){0.f, 0.f, 0.f, 0.f};
    S[3] = (f32x4){0.f, 0.f, 0.f, 0.f};
#pragma unroll
    for (int khf = 0; khf < 2; ++khf) {
      const int cc = khf * 4 + g;
#pragma unroll
      for (int tt = 0; tt < 4; ++tt) {
        const int row = 16 * tt + li;
        bf16x8 akh = *(const bf16x8*)&KhS[swzi(row, cc)];
        bf16x8 akl = *(const bf16x8*)&KlS[swzi(row, cc)];
        S[tt] = __builtin_amdgcn_mfma_f32_16x16x32_bf16(akh, qfh[khf], S[tt], 0, 0, 0);
        S[tt] = __builtin_amdgcn_mfma_f32_16x16x32_bf16(akh, qfl[khf], S[tt], 0, 0, 0);
        S[tt] = __builtin_amdgcn_mfma_f32_16x16x32_bf16(akl, qfh[khf], S[tt], 0, 0, 0);
      }
    }

    // Online softmax (log2 domain; scale pre-folded into Q).
    float mloc = -1e30f;
#pragma unroll
    for (int tt = 0; tt < 4; ++tt)
#pragma unroll
      for (int rr = 0; rr < 4; ++rr) mloc = fmaxf(mloc, S[tt][rr]);
    mloc = fmaxf(mloc, __shfl_xor(mloc, 16));
    mloc = fmaxf(mloc, __shfl_xor(mloc, 32));
    const float mnew  = fmaxf(m, mloc);
    const float alpha = exp2f(m - mnew);
    float ls = 0.f;
#pragma unroll
    for (int tt = 0; tt < 4; ++tt)
#pragma unroll
      for (int rr = 0; rr < 4; ++rr) {
        const float p = exp2f(S[tt][rr] - mnew);
        S[tt][rr] = p;
        ls += p;
      }
    ls += __shfl_xor(ls, 16);
    ls += __shfl_xor(ls, 32);
    lsum = lsum * alpha + ls;
    m = mnew;

    // P^T -> LDS as bf16 (rows 16w..16w+15: wave-local, no barrier needed).
#pragma unroll
    for (int tt = 0; tt < 4; ++tt) {
      const int key = 16 * tt + 4 * g;
      const int idx = prow * 64 + (((key >> 3) ^ (prow & 7)) << 3) + (key & 7);
      const unsigned int p01 =
          (unsigned int)f2bf(S[tt][0]) | ((unsigned int)f2bf(S[tt][1]) << 16);
      const unsigned int p23 =
          (unsigned int)f2bf(S[tt][2]) | ((unsigned int)f2bf(S[tt][3]) << 16);
      *(unsigned int*)&PtS[idx]     = p01;
      *(unsigned int*)&PtS[idx + 2] = p23;
    }

    // Rescale O rows by alpha (O row = 4g+r; alpha lives at lane q-local).
    {
      const float a0 = __shfl(alpha, 4 * g + 0);
      const float a1 = __shfl(alpha, 4 * g + 1);
      const float a2 = __shfl(alpha, 4 * g + 2);
      const float a3 = __shfl(alpha, 4 * g + 3);
#pragma unroll
      for (int n = 0; n < 4; ++n) {
        O[n][0] *= a0; O[n][1] *= a1; O[n][2] *= a2; O[n][3] *= a3;
      }
    }

    // Compiler barrier: keep P^T ds_writes before the ds_reads below
    // (HW DS pipe is in-order per wave; reads are wave-local rows).
    asm volatile("" ::: "memory");

    // O += P^T . V   (A = P^T rows q, B = V^T rows h, both b128 swizzled)
#pragma unroll
    for (int khf = 0; khf < 2; ++khf) {
      const int cc = khf * 4 + g;
      bf16x8 pa = *(const bf16x8*)&PtS[swzi(prow, cc)];
#pragma unroll
      for (int n = 0; n < 4; ++n) {
        bf16x8 vb = *(const bf16x8*)&VtS[swzi(16 * n + li, cc)];
        O[n] = __builtin_amdgcn_mfma_f32_16x16x32_bf16(pa, vb, O[n], 0, 0, 0);
      }
    }
  }

  // Epilogue: O /= l, store fp32. O row = q0+16w+4g+r, col = 16n+li.
  const float l0 = __shfl(lsum, 4 * g + 0);
  const float l1 = __shfl(lsum, 4 * g + 1);
  const float l2 = __shfl(lsum, 4 * g + 2);
  const float l3 = __shfl(lsum, 4 * g + 3);
  const float i0 = 1.f / l0, i1 = 1.f / l1, i2 = 1.f / l2, i3 = 1.f / l3;
  const int qbase = b * SEQ + q0 + 16 * w + 4 * g;
#pragma unroll
  for (int n = 0; n < 4; ++n) {
    out[(qbase + 0) * HS + 16 * n + li] = O[n][0] * i0;
    out[(qbase + 1) * HS + 16 * n + li] = O[n][1] * i1;
    out[(qbase + 2) * HS + 16 * n + li] = O[n][2] * i2;
    out[(qbase + 3) * HS + 16 * n + li] = O[n][3] * i3;
  }
}

// ---------------------------------------------------------------------------
extern "C" void kernel_launch(void* const* d_in, const int* in_sizes, int n_in,
                              void* d_out, int out_size, void* d_ws,
                              size_t ws_size, hipStream_t stream) {
  const float* x  = (const float*)d_in[0];
  const float* Wk = (const float*)d_in[1];
  const float* Wq = (const float*)d_in[2];
  const float* Wv = (const float*)d_in[3];
  float* out = (float*)d_out;

  // ws: 5 bf16 arrays of B*N*H = 1M elems each (10 MB total)
  unsigned short* us = (unsigned short*)d_ws;
  unsigned short* qh = us + 0 * (1 << 20);
  unsigned short* ql = us + 1 * (1 << 20);
  unsigned short* kh = us + 2 * (1 << 20);
  unsigned short* kl = us + 3 * (1 << 20);
  unsigned short* vt = us + 4 * (1 << 20);

  qkv_proj<<<dim3(256, 3), 256, 0, stream>>>(x, Wq, Wk, Wv, qh, ql, kh, kl, vt);
  attn_mfma<<<dim3(64, NB), 256, 0, stream>>>(qh, ql, kh, kl, vt, out);
}